// Round 1
// baseline (315.600 us; speedup 1.0000x reference)
//
#include <hip/hip_runtime.h>
#include <stdint.h>

#define IN_F   4096
#define OUT_F  4096
#define BATCH  4096

#define BM 128
#define BN 128
#define BK 32

typedef __bf16 bf16x8 __attribute__((ext_vector_type(8)));
typedef float  f32x4  __attribute__((ext_vector_type(4)));

// ---------- fp32 -> bf16 (round-to-nearest-even), vectorized ----------
__device__ inline unsigned short f32_to_bf16_rne(float f) {
    unsigned int u = __float_as_uint(f);
    u += 0x7FFFu + ((u >> 16) & 1u);
    return (unsigned short)(u >> 16);
}

__global__ void cvt_f32_bf16(const float4* __restrict__ in,
                             ushort4* __restrict__ out, int n4) {
    int i = blockIdx.x * blockDim.x + threadIdx.x;
    if (i < n4) {
        float4 v = in[i];
        ushort4 o;
        o.x = f32_to_bf16_rne(v.x);
        o.y = f32_to_bf16_rne(v.y);
        o.z = f32_to_bf16_rne(v.z);
        o.w = f32_to_bf16_rne(v.w);
        out[i] = o;
    }
}

// ---------- async global->LDS, 16B per lane ----------
__device__ inline void async_load16(const void* g, void* l) {
    __builtin_amdgcn_global_load_lds(
        (const __attribute__((address_space(1))) unsigned int*)g,
        (__attribute__((address_space(3))) unsigned int*)l,
        16, 0, 0);
}

// ---------- m97-structure bf16 GEMM: C = A * Bt^T + bias ----------
// A: [BATCH][IN_F] bf16 bits, Bt: [OUT_F][IN_F] bf16 bits (both K-contiguous)
__global__ void gemm_bt_bf16(const unsigned short* __restrict__ A,
                             const unsigned short* __restrict__ Bt,
                             const float* __restrict__ bias,
                             float* __restrict__ out) {
    __shared__ unsigned short lsA[BM * BK];  // 8 KB, unpadded (global_load_lds layout)
    __shared__ unsigned short lsB[BN * BK];  // 8 KB

    const int tid  = threadIdx.x;
    const int lane = tid & 63;
    const int wv   = tid >> 6;          // wave 0..3
    const int wm   = (wv & 1) * 64;     // wave M offset within tile
    const int wn   = (wv >> 1) * 64;    // wave N offset within tile

    const int m0 = blockIdx.y * BM;
    const int n0 = blockIdx.x * BN;

    // Staging: each wave stages two 16-row chunks of A and of B per K-step.
    // One global_load_lds(16B): lane l -> LDS base + l*16
    //   => row = chunk_row0 + l/4, col elems (l%4)*8 .. +8  (row stride 32 elems = 64B)
    const int srow = lane >> 2;        // 0..15
    const int scol = (lane & 3) * 8;   // 0,8,16,24

    const unsigned short* gA0 = A  + (size_t)(m0 + wv * 32 + srow) * IN_F + scol;
    const unsigned short* gA1 = gA0 + 16 * (size_t)IN_F;
    const unsigned short* gB0 = Bt + (size_t)(n0 + wv * 32 + srow) * IN_F + scol;
    const unsigned short* gB1 = gB0 + 16 * (size_t)IN_F;

    unsigned short* lA0 = &lsA[(wv * 32)      * BK];
    unsigned short* lA1 = &lsA[(wv * 32 + 16) * BK];
    unsigned short* lB0 = &lsB[(wv * 32)      * BK];
    unsigned short* lB1 = &lsB[(wv * 32 + 16) * BK];

    // MFMA A/B-operand layout: row (m or n) = lane&15, k = (lane>>4)*8 + j
    const int fr = lane & 15;
    const int kq = (lane >> 4) * 8;

    f32x4 acc[4][4] = {};

    for (int kt = 0; kt < IN_F; kt += BK) {
        async_load16(gA0, lA0);
        async_load16(gA1, lA1);
        async_load16(gB0, lB0);
        async_load16(gB1, lB1);
        gA0 += BK; gA1 += BK; gB0 += BK; gB1 += BK;
        __syncthreads();   // drains vmcnt -> LDS tile visible

        bf16x8 aF[4], bF[4];
        #pragma unroll
        for (int i = 0; i < 4; ++i)
            aF[i] = *(const bf16x8*)&lsA[(wm + i * 16 + fr) * BK + kq];
        #pragma unroll
        for (int j = 0; j < 4; ++j)
            bF[j] = *(const bf16x8*)&lsB[(wn + j * 16 + fr) * BK + kq];

        #pragma unroll
        for (int i = 0; i < 4; ++i)
            #pragma unroll
            for (int j = 0; j < 4; ++j)
                acc[i][j] = __builtin_amdgcn_mfma_f32_16x16x32_bf16(
                    aF[i], bF[j], acc[i][j], 0, 0, 0);
        __syncthreads();   // protect LDS before next stage
    }

    // Epilogue. C/D layout (verified m89/m91): col = lane&15, row = (lane>>4)*4 + reg
    const int ocol = n0 + wn;
    float bj[4];
    #pragma unroll
    for (int j = 0; j < 4; ++j) bj[j] = bias[ocol + j * 16 + fr];

    const int rsel = (lane >> 4) * 4;
    #pragma unroll
    for (int i = 0; i < 4; ++i) {
        #pragma unroll
        for (int v = 0; v < 4; ++v) {
            const int row = m0 + wm + i * 16 + rsel + v;
            float* orow = out + (size_t)row * OUT_F + ocol + fr;
            #pragma unroll
            for (int j = 0; j < 4; ++j)
                orow[j * 16] = acc[i][j][v] + bj[j];
        }
    }
}

// ---------- fallback: correct fp32 tiled GEMM (only if ws too small) ----------
__global__ void fb_gemm(const float* __restrict__ A, const float* __restrict__ W,
                        const float* __restrict__ bias, float* __restrict__ out) {
    __shared__ float tA[16][17];
    __shared__ float tW[16][17];
    const int tx = threadIdx.x, ty = threadIdx.y;
    const int row = blockIdx.y * 16 + ty;
    const int col = blockIdx.x * 16 + tx;
    float s = 0.f;
    for (int k = 0; k < IN_F; k += 16) {
        tA[ty][tx] = A[(size_t)row * IN_F + k + tx];
        tW[ty][tx] = W[(size_t)(blockIdx.x * 16 + ty) * IN_F + k + tx];
        __syncthreads();
        #pragma unroll
        for (int kk = 0; kk < 16; ++kk) s += tA[ty][kk] * tW[tx][kk];
        __syncthreads();
    }
    out[(size_t)row * OUT_F + col] = s + bias[col];
}

extern "C" void kernel_launch(void* const* d_in, const int* in_sizes, int n_in,
                              void* d_out, int out_size, void* d_ws, size_t ws_size,
                              hipStream_t stream) {
    const float* x = (const float*)d_in[0];
    const float* W = (const float*)d_in[1];
    const float* b = (const float*)d_in[2];
    float* out = (float*)d_out;

    const size_t elems      = (size_t)BATCH * IN_F;  // 16.7M per matrix
    const size_t bf16_bytes = elems * 2;             // 32 MiB each

    if (ws_size >= 2 * bf16_bytes) {
        unsigned short* xb = (unsigned short*)d_ws;
        unsigned short* wb = (unsigned short*)((char*)d_ws + bf16_bytes);

        const int n4 = (int)(elems / 4);
        const int cblocks = (n4 + 255) / 256;
        cvt_f32_bf16<<<cblocks, 256, 0, stream>>>((const float4*)x, (ushort4*)xb, n4);
        cvt_f32_bf16<<<cblocks, 256, 0, stream>>>((const float4*)W, (ushort4*)wb, n4);

        dim3 grid(OUT_F / BN, BATCH / BM);  // 32 x 32
        gemm_bt_bf16<<<grid, 256, 0, stream>>>(xb, wb, b, out);
    } else {
        dim3 grid(OUT_F / 16, BATCH / 16);
        fb_gemm<<<grid, dim3(16, 16), 0, stream>>>(x, W, b, out);
    }
}